// Round 13
// baseline (637.560 us; speedup 1.0000x reference)
//
#include <hip/hip_runtime.h>
#include <hip/hip_bf16.h>

typedef __attribute__((ext_vector_type(8))) short short8;
typedef __attribute__((ext_vector_type(4))) float f32x4;

#define D_DIM 256
#define G_DIM 256
#define NSEG 4096
#define BM 64
#define LOG2E 1.4426950408889634f

__device__ __forceinline__ unsigned f2bf_u(float f) {
  unsigned u = __builtin_bit_cast(unsigned, f);
  return (u + 0x7fffu + ((u >> 16) & 1u)) >> 16;   // RNE, inputs are finite
}
__device__ __forceinline__ unsigned pk_bf2(float a, float b) {
  __hip_bfloat162 h = __float22bfloat162_rn(float2{a, b});  // v_cvt_pk_bf16_f32
  unsigned r;
  __builtin_memcpy(&r, &h, 4);
  return r;
}

// 16-lane-group sum via DPP (VALU-only, no LDS pipe)
template <int CTRL>
__device__ __forceinline__ float dpp_add(float v) {
  int x = __builtin_bit_cast(int, v);
  int y = __builtin_amdgcn_update_dpp(0, x, CTRL, 0xF, 0xF, true);
  return v + __builtin_bit_cast(float, y);
}
__device__ __forceinline__ float row16_sum(float v) {
  v = dpp_add<0xB1>(v);   // quad_perm [1,0,3,2]  (xor 1)
  v = dpp_add<0x4E>(v);   // quad_perm [2,3,0,1]  (xor 2)
  v = dpp_add<0x124>(v);  // row_ror:4
  v = dpp_add<0x128>(v);  // row_ror:8
  return v;               // all 16 lanes of the row hold the sum
}

// ---- W/Wg -> bf16 transposed (+log2e prescale on Wg) + zero seg/counts ----
// Gate path computes exp2((x@Wg')+bg') with Wg'=Wg*log2e, bg'=bg*log2e ==
// exp((x@Wg)+bg) exactly; saves one v_mul per gate element in fused_main.
__global__ void wconv_kernel(const float* __restrict__ W, const float* __restrict__ Wg,
                             unsigned short* __restrict__ Wc,
                             float* __restrict__ seg, float* __restrict__ counts) {
  int j = blockIdx.x;          // 0..511
  int k = threadIdx.x;         // 0..255
  float v = (j < 256) ? W[k * 256 + j] : Wg[k * 256 + (j - 256)] * LOG2E;
  Wc[j * 256 + k] = (unsigned short)f2bf_u(v);
  // zero seg (4096*256 = 1,048,576 floats): 131072 threads x 2 float4
  const int tid = j * 256 + k;
  const float4 z = {0.f, 0.f, 0.f, 0.f};
  ((float4*)seg)[tid * 2] = z;
  ((float4*)seg)[tid * 2 + 1] = z;
  if (tid < 1024) ((float4*)counts)[tid] = z;   // 4096 floats
}

// ---- fused: dual GEMM (states|gates) -> softmax gate -> segment partial sums ----
// block: 64 rows x 512 cols, 8 waves of 64; wave w owns cols [w*32, w*32+32) of BOTH halves.
// R12 body, plus: (a) exp2 gate path (prescaled Wg/bg), (b) fast-path epilogue for
// single-segment tiles (74%: g0==g1 -> no rb loads, no predication, pc=64).
__global__ __launch_bounds__(512, 4) void fused_main(
    const float* __restrict__ x, const int* __restrict__ batch,
    const unsigned short* __restrict__ Wc,
    const float* __restrict__ bvec, const float* __restrict__ bgvec,
    float* __restrict__ seg, float* __restrict__ counts, int N) {
  __shared__ __align__(16) char xs[32768];        // x tile [64][256] bf16, swizzled
  __shared__ __align__(16) float part[8][64];     // per-wave row partial sums
  __shared__ __align__(16) float sinv[64];        // 1/rowsum

  const int t = threadIdx.x;
  const int lane = t & 63;
  const int wid = t >> 6;                         // 0..7
  const int lr = lane & 15;
  const int lk = lane >> 4;
  const long row0 = (long)blockIdx.x * BM;        // N % 64 == 0 (1e6 = 15625*64)

  // stage x tile [64][256] as bf16, swizzle: byte ^= (row&7)<<4   (4 iters x 512 thr)
#pragma unroll
  for (int it = 0; it < 4; ++it) {
    int rl = it * 16 + (t >> 5);
    int kb = (t & 31) * 8;
    const float4* p = (const float4*)(x + (row0 + rl) * D_DIM + kb);
    float4 v0 = p[0], v1 = p[1];
    uint4 pk;
    pk.x = pk_bf2(v0.x, v0.y);
    pk.y = pk_bf2(v0.z, v0.w);
    pk.z = pk_bf2(v1.x, v1.y);
    pk.w = pk_bf2(v1.z, v1.w);
    int byte = (rl * 512 + kb * 2) ^ ((rl & 7) << 4);
    *(uint4*)(xs + byte) = pk;
  }
  __syncthreads();

  // K-loop, fully unrolled; B-frags direct from global (Wc 256KB, L2-resident).
  // acc n: 0,1 = states cols cb..cb+32; 2,3 = gates cols cb..cb+32.
  f32x4 acc[4][4];
#pragma unroll
  for (int m = 0; m < 4; ++m)
#pragma unroll
    for (int n = 0; n < 4; ++n) acc[m][n] = (f32x4){0.f, 0.f, 0.f, 0.f};

  const int cb = wid * 32;
  __builtin_amdgcn_s_setprio(1);
#pragma unroll
  for (int kk = 0; kk < 8; ++kk) {
    const int k0 = kk * 32 + lk * 8;
    short8 a[4], bb[4];
#pragma unroll
    for (int n = 0; n < 4; ++n) {
      int col = (n < 2) ? (cb + n * 16 + lr) : (256 + cb + (n - 2) * 16 + lr);
      bb[n] = *(const short8*)(Wc + col * 256 + k0);
    }
#pragma unroll
    for (int m = 0; m < 4; ++m) {
      int row = m * 16 + lr;
      int byte = (row * 512 + k0 * 2) ^ ((row & 7) << 4);
      a[m] = *(const short8*)(xs + byte);
    }
#pragma unroll
    for (int m = 0; m < 4; ++m)
#pragma unroll
      for (int n = 0; n < 4; ++n)
        acc[m][n] = __builtin_amdgcn_mfma_f32_16x16x32_bf16(a[m], bb[n], acc[m][n], 0, 0, 0);
  }
  __builtin_amdgcn_s_setprio(0);

  // segment span (scalar loads, uniform addresses)
  const int g0 = batch[row0];
  const int g1 = batch[row0 + BM - 1];

  // gates: e = exp2(logit' + bg')  == exp(logit + bg)  (Wg/bg prescaled by log2e)
  float bgv[2];
#pragma unroll
  for (int n = 0; n < 2; ++n) bgv[n] = bgvec[cb + n * 16 + lr] * LOG2E;
#pragma unroll
  for (int m = 0; m < 4; ++m)
#pragma unroll
    for (int n = 2; n < 4; ++n)
#pragma unroll
      for (int q = 0; q < 4; ++q)
        acc[m][n][q] = exp2f(acc[m][n][q] + bgv[n - 2]);

  // wave-local row sums over this wave's 32 gate cols:
  // C layout: row = m*16 + lk*4 + q, col = n*16 + lr. Reduce over n (regs) then lr (DPP).
#pragma unroll
  for (int m = 0; m < 4; ++m) {
    float s[4];
#pragma unroll
    for (int q = 0; q < 4; ++q) s[q] = row16_sum(acc[m][2][q] + acc[m][3][q]);
    if (lr == 0) {
#pragma unroll
      for (int q = 0; q < 4; ++q) part[wid][m * 16 + lk * 4 + q] = s[q];
    }
  }
  __syncthreads();
  if (wid == 0) {
    float v = part[0][lane] + part[1][lane] + part[2][lane] + part[3][lane] +
              part[4][lane] + part[5][lane] + part[6][lane] + part[7][lane];
    sinv[lane] = 1.0f / v;
  }
  __syncthreads();

  // gating: gated = (states + b) * e * sinv
  float bv[2];
#pragma unroll
  for (int n = 0; n < 2; ++n) bv[n] = bvec[cb + n * 16 + lr];
  f32x4 siv[4];
#pragma unroll
  for (int m = 0; m < 4; ++m) siv[m] = *(const f32x4*)(&sinv[m * 16 + lk * 4]);
#pragma unroll
  for (int m = 0; m < 4; ++m)
#pragma unroll
    for (int n = 0; n < 2; ++n)
#pragma unroll
      for (int q = 0; q < 4; ++q)
        acc[m][n][q] = (acc[m][n][q] + bv[n]) * acc[m][n + 2][q] * siv[m][q];

  if (g0 == g1) {
    // ---- fast path (74% of tiles): whole tile in one segment ----
    float p[2] = {0.f, 0.f};
#pragma unroll
    for (int m = 0; m < 4; ++m)
#pragma unroll
      for (int q = 0; q < 4; ++q) {
#pragma unroll
        for (int n = 0; n < 2; ++n) p[n] += acc[m][n][q];
      }
#pragma unroll
    for (int n = 0; n < 2; ++n) {
      p[n] += __shfl_xor(p[n], 16);
      p[n] += __shfl_xor(p[n], 32);
    }
    if (lane < 16) {
#pragma unroll
      for (int n = 0; n < 2; ++n)
        atomicAdd(seg + (long)g0 * G_DIM + cb + n * 16 + lane, p[n]);
    }
    if (wid == 0 && lane == 0) atomicAdd(counts + g0, 64.f);
  } else {
    // ---- slow path: tile spans multiple segments; predicated per-g reduce ----
    int rb[4][4];
#pragma unroll
    for (int m = 0; m < 4; ++m) {
      const int4 v = *(const int4*)(batch + row0 + m * 16 + lk * 4);
      rb[m][0] = v.x; rb[m][1] = v.y; rb[m][2] = v.z; rb[m][3] = v.w;
    }
    for (int g = g0; g <= g1; ++g) {
      float p[2] = {0.f, 0.f};
      float pc = 0.f;
#pragma unroll
      for (int m = 0; m < 4; ++m)
#pragma unroll
        for (int q = 0; q < 4; ++q) {
          bool hit = (rb[m][q] == g);
          pc += hit ? 1.f : 0.f;
#pragma unroll
          for (int n = 0; n < 2; ++n) p[n] += hit ? acc[m][n][q] : 0.f;
        }
#pragma unroll
      for (int n = 0; n < 2; ++n) {
        p[n] += __shfl_xor(p[n], 16);
        p[n] += __shfl_xor(p[n], 32);
      }
      pc += __shfl_xor(pc, 16);
      pc += __shfl_xor(pc, 32);
      if (lane < 16) {
#pragma unroll
        for (int n = 0; n < 2; ++n)
          atomicAdd(seg + (long)g * G_DIM + cb + n * 16 + lane, p[n]);
      }
      if (wid == 0 && lane == 0) atomicAdd(counts + g, pc);
    }
  }
}

// ---- out = (seg/max(cnt,1)) @ Wf + bf, in-place on d_out (block-local staging) ----
__global__ __launch_bounds__(256) void final_kernel(
    float* __restrict__ seg, const float* __restrict__ counts,
    const float* __restrict__ Wf, const float* __restrict__ bfv) {
  __shared__ float mlds[16][257];
  int g0 = blockIdx.x * 16;
  int t = threadIdx.x;
#pragma unroll
  for (int i = 0; i < 16; ++i) {
    float inv = 1.0f / fmaxf(counts[g0 + i], 1.0f);
    mlds[i][t] = seg[(g0 + i) * 256 + t] * inv;
  }
  __syncthreads();
  float a[16];
#pragma unroll
  for (int i = 0; i < 16; ++i) a[i] = 0.f;
  for (int k = 0; k < 256; ++k) {
    float w = Wf[k * 256 + t];
#pragma unroll
    for (int i = 0; i < 16; ++i) a[i] += mlds[i][k] * w;
  }
  float bfx = bfv[t];
#pragma unroll
  for (int i = 0; i < 16; ++i) seg[(g0 + i) * 256 + t] = a[i] + bfx;
}

extern "C" void kernel_launch(void* const* d_in, const int* in_sizes, int n_in,
                              void* d_out, int out_size, void* d_ws, size_t ws_size,
                              hipStream_t stream) {
  const float* x = (const float*)d_in[0];
  const int* batch = (const int*)d_in[1];
  const float* W = (const float*)d_in[2];
  const float* b = (const float*)d_in[3];
  const float* Wg = (const float*)d_in[4];
  const float* bg = (const float*)d_in[5];
  const float* Wf = (const float*)d_in[6];
  const float* bf = (const float*)d_in[7];
  const int N = in_sizes[0] / D_DIM;  // 1,000,000

  unsigned short* Wc = (unsigned short*)d_ws;              // 512*256*2 = 262144 B
  float* counts = (float*)((char*)d_ws + 262144);          // 4096*4 = 16384 B
  float* seg = (float*)d_out;                              // seg_sum scratch == output buffer

  hipLaunchKernelGGL(wconv_kernel, dim3(512), dim3(256), 0, stream, W, Wg, Wc, seg, counts);
  hipLaunchKernelGGL(fused_main, dim3(N / BM), dim3(512), 0, stream, x, batch, Wc, b, bg, seg,
                     counts, N);
  hipLaunchKernelGGL(final_kernel, dim3(NSEG / 16), dim3(256), 0, stream, seg, counts, Wf, bf);
}

// Round 14
// 629.976 us; speedup vs baseline: 1.0120x; 1.0120x over previous
//
#include <hip/hip_runtime.h>
#include <hip/hip_bf16.h>

typedef __attribute__((ext_vector_type(8))) short short8;
typedef __attribute__((ext_vector_type(4))) float f32x4;

#define D_DIM 256
#define G_DIM 256
#define NSEG 4096
#define BM 64

__device__ __forceinline__ unsigned f2bf_u(float f) {
  unsigned u = __builtin_bit_cast(unsigned, f);
  return (u + 0x7fffu + ((u >> 16) & 1u)) >> 16;   // RNE, inputs are finite
}
__device__ __forceinline__ unsigned pk_bf2(float a, float b) {
  __hip_bfloat162 h = __float22bfloat162_rn(float2{a, b});  // v_cvt_pk_bf16_f32
  unsigned r;
  __builtin_memcpy(&r, &h, 4);
  return r;
}

// 16-lane-group sum via DPP (VALU-only, no LDS pipe)
template <int CTRL>
__device__ __forceinline__ float dpp_add(float v) {
  int x = __builtin_bit_cast(int, v);
  int y = __builtin_amdgcn_update_dpp(0, x, CTRL, 0xF, 0xF, true);
  return v + __builtin_bit_cast(float, y);
}
__device__ __forceinline__ float row16_sum(float v) {
  v = dpp_add<0xB1>(v);   // quad_perm [1,0,3,2]  (xor 1)
  v = dpp_add<0x4E>(v);   // quad_perm [2,3,0,1]  (xor 2)
  v = dpp_add<0x124>(v);  // row_ror:4
  v = dpp_add<0x128>(v);  // row_ror:8
  return v;               // all 16 lanes of the row hold the sum
}

// ---- W/Wg -> bf16 transposed + zero seg/counts (replaces memset + count_kernel's zeroing) ----
__global__ void wconv_kernel(const float* __restrict__ W, const float* __restrict__ Wg,
                             unsigned short* __restrict__ Wc,
                             float* __restrict__ seg, float* __restrict__ counts) {
  int j = blockIdx.x;          // 0..511
  int k = threadIdx.x;         // 0..255
  float v = (j < 256) ? W[k * 256 + j] : Wg[k * 256 + (j - 256)];
  Wc[j * 256 + k] = (unsigned short)f2bf_u(v);
  // zero seg (4096*256 = 1,048,576 floats): 131072 threads x 2 float4
  const int tid = j * 256 + k;
  const float4 z = {0.f, 0.f, 0.f, 0.f};
  ((float4*)seg)[tid * 2] = z;
  ((float4*)seg)[tid * 2 + 1] = z;
  if (tid < 1024) ((float4*)counts)[tid] = z;   // 4096 floats
}

// ---- fused: dual GEMM (states|gates) -> softmax gate -> segment partial sums ----
// block: 64 rows x 512 cols, 8 waves of 64; wave w owns cols [w*32, w*32+32) of BOTH halves.
// R5 body (639us) verbatim, plus: per-segment row COUNT accumulated in the existing
// shfl reduce and atomically added by wave 0 (replaces the binary-search count_kernel,
// whose ~40-deep dependent-load chain was pure serial stream latency).
// Frozen invariants (falsified alternatives): 1 tile per block, in dispatch order
// (R7/R10: any other mapping blows up FETCH 0.5->1.2-3.2GB); 512 thr / 4 waves/SIMD
// (R8/R9: higher occupancy spills or runs slower); no explicit pipelining
// (R3/R6/R11: neutral to -66%).
__global__ __launch_bounds__(512, 4) void fused_main(
    const float* __restrict__ x, const int* __restrict__ batch,
    const unsigned short* __restrict__ Wc,
    const float* __restrict__ bvec, const float* __restrict__ bgvec,
    float* __restrict__ seg, float* __restrict__ counts, int N) {
  __shared__ __align__(16) char xs[32768];        // x tile [64][256] bf16, swizzled
  __shared__ __align__(16) float part[8][64];     // per-wave row partial sums
  __shared__ __align__(16) float sinv[64];        // 1/rowsum

  const int t = threadIdx.x;
  const int lane = t & 63;
  const int wid = t >> 6;                         // 0..7
  const int lr = lane & 15;
  const int lk = lane >> 4;
  const long row0 = (long)blockIdx.x * BM;        // N % 64 == 0 (1e6 = 15625*64)

  // stage x tile [64][256] as bf16, swizzle: byte ^= (row&7)<<4   (4 iters x 512 thr)
#pragma unroll
  for (int it = 0; it < 4; ++it) {
    int rl = it * 16 + (t >> 5);
    int kb = (t & 31) * 8;
    const float4* p = (const float4*)(x + (row0 + rl) * D_DIM + kb);
    float4 v0 = p[0], v1 = p[1];
    uint4 pk;
    pk.x = pk_bf2(v0.x, v0.y);
    pk.y = pk_bf2(v0.z, v0.w);
    pk.z = pk_bf2(v1.x, v1.y);
    pk.w = pk_bf2(v1.z, v1.w);
    int byte = (rl * 512 + kb * 2) ^ ((rl & 7) << 4);
    *(uint4*)(xs + byte) = pk;
  }
  __syncthreads();

  // K-loop, fully unrolled; B-frags direct from global (Wc 256KB, L2-resident).
  // acc n: 0,1 = states cols cb..cb+32; 2,3 = gates cols cb..cb+32.
  f32x4 acc[4][4];
#pragma unroll
  for (int m = 0; m < 4; ++m)
#pragma unroll
    for (int n = 0; n < 4; ++n) acc[m][n] = (f32x4){0.f, 0.f, 0.f, 0.f};

  const int cb = wid * 32;
  __builtin_amdgcn_s_setprio(1);
#pragma unroll
  for (int kk = 0; kk < 8; ++kk) {
    const int k0 = kk * 32 + lk * 8;
    short8 a[4], bb[4];
#pragma unroll
    for (int n = 0; n < 4; ++n) {
      int col = (n < 2) ? (cb + n * 16 + lr) : (256 + cb + (n - 2) * 16 + lr);
      bb[n] = *(const short8*)(Wc + col * 256 + k0);
    }
#pragma unroll
    for (int m = 0; m < 4; ++m) {
      int row = m * 16 + lr;
      int byte = (row * 512 + k0 * 2) ^ ((row & 7) << 4);
      a[m] = *(const short8*)(xs + byte);
    }
#pragma unroll
    for (int m = 0; m < 4; ++m)
#pragma unroll
      for (int n = 0; n < 4; ++n)
        acc[m][n] = __builtin_amdgcn_mfma_f32_16x16x32_bf16(a[m], bb[n], acc[m][n], 0, 0, 0);
  }
  __builtin_amdgcn_s_setprio(0);

  // early: batch ids for the segment epilogue (a[]/bb[] just died -> regs free;
  // L2 latency hides under exp/rowsum/gating below)
  int rb[4][4];
#pragma unroll
  for (int m = 0; m < 4; ++m) {
    const int4 v = *(const int4*)(batch + row0 + m * 16 + lk * 4);
    rb[m][0] = v.x; rb[m][1] = v.y; rb[m][2] = v.z; rb[m][3] = v.w;
  }
  const int g0 = batch[row0];
  const int g1 = batch[row0 + BM - 1];

  // gates: e = exp(logit + bg) in fp32 regs (no max-sub: logits ~N(0,1), exp <= ~500)
  float bgv[2];
#pragma unroll
  for (int n = 0; n < 2; ++n) bgv[n] = bgvec[cb + n * 16 + lr];
#pragma unroll
  for (int m = 0; m < 4; ++m)
#pragma unroll
    for (int n = 2; n < 4; ++n)
#pragma unroll
      for (int q = 0; q < 4; ++q)
        acc[m][n][q] = __expf(acc[m][n][q] + bgv[n - 2]);

  // wave-local row sums over this wave's 32 gate cols:
  // C layout: row = m*16 + lk*4 + q, col = n*16 + lr. Reduce over n (regs) then lr (DPP).
#pragma unroll
  for (int m = 0; m < 4; ++m) {
    float s[4];
#pragma unroll
    for (int q = 0; q < 4; ++q) s[q] = row16_sum(acc[m][2][q] + acc[m][3][q]);
    if (lr == 0) {
#pragma unroll
      for (int q = 0; q < 4; ++q) part[wid][m * 16 + lk * 4 + q] = s[q];
    }
  }
  __syncthreads();
  if (wid == 0) {
    float v = part[0][lane] + part[1][lane] + part[2][lane] + part[3][lane] +
              part[4][lane] + part[5][lane] + part[6][lane] + part[7][lane];
    sinv[lane] = 1.0f / v;
  }
  __syncthreads();

  // gating: gated = (states + b) * e * sinv
  float bv[2];
#pragma unroll
  for (int n = 0; n < 2; ++n) bv[n] = bvec[cb + n * 16 + lr];
  f32x4 siv[4];
#pragma unroll
  for (int m = 0; m < 4; ++m) siv[m] = *(const f32x4*)(&sinv[m * 16 + lk * 4]);
#pragma unroll
  for (int m = 0; m < 4; ++m)
#pragma unroll
    for (int n = 0; n < 2; ++n)
#pragma unroll
      for (int q = 0; q < 4; ++q)
        acc[m][n][q] = (acc[m][n][q] + bv[n]) * acc[m][n + 2][q] * siv[m][q];

  // segment reduce: batch sorted -> tile spans [g0, g1] (typically 1-2 segments).
  // pc rides the same reduce: after xor16/32, pc = rows_in_g (identical across
  // waves since rb doesn't depend on wid) -> wave 0 lane 0 adds it to counts[g].
  for (int g = g0; g <= g1; ++g) {
    float p[2] = {0.f, 0.f};
    float pc = 0.f;
#pragma unroll
    for (int m = 0; m < 4; ++m)
#pragma unroll
      for (int q = 0; q < 4; ++q) {
        bool hit = (rb[m][q] == g);
        pc += hit ? 1.f : 0.f;
#pragma unroll
        for (int n = 0; n < 2; ++n) p[n] += hit ? acc[m][n][q] : 0.f;
      }
#pragma unroll
    for (int n = 0; n < 2; ++n) {
      p[n] += __shfl_xor(p[n], 16);
      p[n] += __shfl_xor(p[n], 32);
    }
    pc += __shfl_xor(pc, 16);
    pc += __shfl_xor(pc, 32);
    if (lane < 16) {
#pragma unroll
      for (int n = 0; n < 2; ++n)
        atomicAdd(seg + (long)g * G_DIM + cb + n * 16 + lane, p[n]);
    }
    if (wid == 0 && lane == 0) atomicAdd(counts + g, pc);
  }
}

// ---- out = (seg/max(cnt,1)) @ Wf + bf, in-place on d_out (block-local staging) ----
__global__ __launch_bounds__(256) void final_kernel(
    float* __restrict__ seg, const float* __restrict__ counts,
    const float* __restrict__ Wf, const float* __restrict__ bfv) {
  __shared__ float mlds[16][257];
  int g0 = blockIdx.x * 16;
  int t = threadIdx.x;
#pragma unroll
  for (int i = 0; i < 16; ++i) {
    float inv = 1.0f / fmaxf(counts[g0 + i], 1.0f);
    mlds[i][t] = seg[(g0 + i) * 256 + t] * inv;
  }
  __syncthreads();
  float a[16];
#pragma unroll
  for (int i = 0; i < 16; ++i) a[i] = 0.f;
  for (int k = 0; k < 256; ++k) {
    float w = Wf[k * 256 + t];
#pragma unroll
    for (int i = 0; i < 16; ++i) a[i] += mlds[i][k] * w;
  }
  float bfx = bfv[t];
#pragma unroll
  for (int i = 0; i < 16; ++i) seg[(g0 + i) * 256 + t] = a[i] + bfx;
}

extern "C" void kernel_launch(void* const* d_in, const int* in_sizes, int n_in,
                              void* d_out, int out_size, void* d_ws, size_t ws_size,
                              hipStream_t stream) {
  const float* x = (const float*)d_in[0];
  const int* batch = (const int*)d_in[1];
  const float* W = (const float*)d_in[2];
  const float* b = (const float*)d_in[3];
  const float* Wg = (const float*)d_in[4];
  const float* bg = (const float*)d_in[5];
  const float* Wf = (const float*)d_in[6];
  const float* bf = (const float*)d_in[7];
  const int N = in_sizes[0] / D_DIM;  // 1,000,000

  unsigned short* Wc = (unsigned short*)d_ws;              // 512*256*2 = 262144 B
  float* counts = (float*)((char*)d_ws + 262144);          // 4096*4 = 16384 B
  float* seg = (float*)d_out;                              // seg_sum scratch == output buffer

  hipLaunchKernelGGL(wconv_kernel, dim3(512), dim3(256), 0, stream, W, Wg, Wc, seg, counts);
  hipLaunchKernelGGL(fused_main, dim3(N / BM), dim3(512), 0, stream, x, batch, Wc, b, bg, seg,
                     counts, N);
  hipLaunchKernelGGL(final_kernel, dim3(NSEG / 16), dim3(256), 0, stream, seg, counts, Wf, bf);
}